// Round 16
// baseline (260.306 us; speedup 1.0000x reference)
//
#include <hip/hip_runtime.h>
#include <cstdint>
#include <cstddef>

typedef __attribute__((ext_vector_type(8))) short short8;   // 8 bf16 (4 VGPRs)
typedef __attribute__((ext_vector_type(4))) float f32x4;    // 4 fp32 acc
typedef __attribute__((ext_vector_type(4))) float f4;
typedef __attribute__((ext_vector_type(2))) float f2;
typedef __attribute__((ext_vector_type(4))) unsigned short us4;

#define NN 4096
#define HH 512
#define EE 65536

// async global->LDS, 16B per lane (dest must be linear: base + lane*16)
#define GLOAD(gp, lp) __builtin_amdgcn_global_load_lds( \
    (const __attribute__((address_space(1))) void*)(gp), \
    (__attribute__((address_space(3))) void*)(lp), 16, 0, 0)

__device__ __forceinline__ unsigned short f2bf(float x) {
    union { float f; unsigned u; } un; un.f = x;
    unsigned r = un.u + 0x7fffu + ((un.u >> 16) & 1u);   // round-to-nearest-even
    return (unsigned short)(r >> 16);
}
__device__ __forceinline__ float b2f(unsigned short v) {
    union { unsigned u; float f; } un; un.u = ((unsigned)v) << 16; return un.f;
}

// ---------------- prep: hist+scan (block 0) | cvt (1..4096) | transposes (4097..7936) ----------------
__global__ __launch_bounds__(256) void k_prep(const float* __restrict__ feat,
                                              unsigned short* __restrict__ featb,
                                              const float* __restrict__ W0a,
                                              const float* __restrict__ W0b,
                                              const float* __restrict__ WRa,
                                              const float* __restrict__ WRb,
                                              unsigned short* __restrict__ w0at,
                                              unsigned short* __restrict__ wt,
                                              const int* __restrict__ edst,
                                              int* __restrict__ starts,
                                              int* __restrict__ cursor) {
    __shared__ alignas(16) int cnt[NN];          // 16 KiB, overlaid as tile[32][33]
    __shared__ int wtot4[4], woff4[4];
    const int t = threadIdx.x;
    const int bid = blockIdx.x;
    if (bid == 0) {
        // ---- edge histogram + exclusive scan (also zeroes cursor) ----
        for (int i = t; i < NN; i += 256) { cnt[i] = 0; cursor[i] = 0; }
        __syncthreads();
        const int4* e4 = (const int4*)edst;   // 16384 int4
        for (int b = 0; b < 64; b += 8) {
            int4 v[8];
#pragma unroll
            for (int k = 0; k < 8; ++k)
                v[k] = e4[(b + k) * 256 + t];
#pragma unroll
            for (int k = 0; k < 8; ++k) {
                atomicAdd(&cnt[v[k].x], 1); atomicAdd(&cnt[v[k].y], 1);
                atomicAdd(&cnt[v[k].z], 1); atomicAdd(&cnt[v[k].w], 1);
            }
        }
        __syncthreads();
        const int base = t * 16;
        int c[16]; int s = 0;
#pragma unroll
        for (int i = 0; i < 16; ++i) { c[i] = cnt[base + i]; s += c[i]; }
        const int lane = t & 63, wv = t >> 6;
        int inc = s;
        for (int d = 1; d < 64; d <<= 1) {
            int v = __shfl_up(inc, d);
            if (lane >= d) inc += v;
        }
        if (lane == 63) wtot4[wv] = inc;
        __syncthreads();
        if (t == 0) {
            int a = 0;
            for (int i = 0; i < 4; ++i) { woff4[i] = a; a += wtot4[i]; }
            starts[NN] = a;
        }
        __syncthreads();
        int run = woff4[wv] + inc - s;
#pragma unroll
        for (int i = 0; i < 16; ++i) { starts[base + i] = run; run += c[i]; }
    } else if (bid <= 4096) {
        // ---- pure cvt stream: feat f32 -> featb bf16, 16 KiB per block ----
        const int b2 = bid - 1;
        const long B0 = (long)b2 * 1024;
        const f4* ff = (const f4*)feat;
        f4 v[4];
#pragma unroll
        for (int k = 0; k < 4; ++k)
            v[k] = __builtin_nontemporal_load(ff + B0 + k * 256 + t);
#pragma unroll
        for (int k = 0; k < 4; ++k) {
            us4 o;
            o.x = f2bf(v[k].x); o.y = f2bf(v[k].y); o.z = f2bf(v[k].z); o.w = f2bf(v[k].w);
            __builtin_nontemporal_store(o, (us4*)featb + B0 + k * 256 + t);
        }
    } else {
        // ---- weight transpose/convert tiles ----
        float (*tile)[33] = (float(*)[33])cnt;
        const int tix = bid - 4097;
        const float* W; unsigned short* Wt; int K, kb, nb;
        if (tix < 2048) {                 // W0a: 128 x 16 tiles of 32x32
            W = W0a; Wt = w0at; K = NN; kb = tix >> 4; nb = tix & 15;
        } else {
            const int t2 = tix - 2048;    // 7 x 256 tiles
            const int z = t2 >> 8, r = t2 & 255;
            W = (z == 0) ? W0b : (z < 4) ? WRa + (size_t)(z - 1) * HH * HH
                                         : WRb + (size_t)(z - 4) * HH * HH;
            Wt = wt + (size_t)z * HH * HH; K = HH; kb = r >> 4; nb = r & 15;
        }
        const int k0 = kb * 32, n0 = nb * 32;
        const int tx = t & 31, ty = t >> 5;
        for (int r = ty; r < 32; r += 8)
            tile[r][tx] = W[(size_t)(k0 + r) * HH + n0 + tx];
        __syncthreads();
        for (int r = ty; r < 32; r += 8)
            Wt[(size_t)(n0 + r) * K + k0 + tx] = f2bf(tile[tx][r]);
    }
}

// ------- gemm0 (0..511) + scatter (512..767) + featb.Wp0 readout dot (768..1791) -------
// gemm0: 128x128 tile, BK=64, 4 waves, split-K=4, XOR-swizzled LDS. 2 blocks/CU.
// dot blocks ride on gemm0's idle memory bandwidth.
__global__ __launch_bounds__(256) void k_gemm0s(
    const unsigned short* __restrict__ A, const unsigned short* __restrict__ Bt,
    float* __restrict__ outf,
    const int* __restrict__ esrc, const int* __restrict__ edst,
    const int* __restrict__ starts, int* __restrict__ cursor, int* __restrict__ sorted,
    const float* __restrict__ Wp0, float* __restrict__ part)
{
    constexpr int K = NN, N = HH;
    __shared__ alignas(16) unsigned short As[2 * 8192];   // 2 x 128x64 = 32 KiB
    __shared__ alignas(16) unsigned short Bs[2 * 8192];   // 32 KiB
    const int bid = blockIdx.x;
    const int t = threadIdx.x;
    if (bid >= 768) {
        // ---- featb . Wp0 partial dot (bf16 feat; error ~1e-2, far below threshold) ----
        const int db = bid - 768;                 // 0..1023
        const long c0 = (long)db * 2048;          // 8-elem chunk base (16384 elems/block)
        const short8* fb = (const short8*)A;      // featb
        const f4* wp = (const f4*)Wp0;
        float a0 = 0.f, a1 = 0.f;
#pragma unroll
        for (int k = 0; k < 8; ++k) {
            const long ci = c0 + k * 256 + t;
            short8 fv = fb[ci];
            f4 w0 = __builtin_nontemporal_load(wp + ci * 4);
            f4 w1 = __builtin_nontemporal_load(wp + ci * 4 + 1);
            f4 w2 = __builtin_nontemporal_load(wp + ci * 4 + 2);
            f4 w3 = __builtin_nontemporal_load(wp + ci * 4 + 3);
            float f0 = b2f((unsigned short)fv[0]), f1 = b2f((unsigned short)fv[1]);
            float f2v = b2f((unsigned short)fv[2]), f3 = b2f((unsigned short)fv[3]);
            float f4v = b2f((unsigned short)fv[4]), f5 = b2f((unsigned short)fv[5]);
            float f6 = b2f((unsigned short)fv[6]), f7 = b2f((unsigned short)fv[7]);
            a0 += f0 * w0.x + f1 * w0.z + f2v * w1.x + f3 * w1.z
                + f4v * w2.x + f5 * w2.z + f6 * w3.x + f7 * w3.z;
            a1 += f0 * w0.y + f1 * w0.w + f2v * w1.y + f3 * w1.w
                + f4v * w2.y + f5 * w2.w + f6 * w3.y + f7 * w3.w;
        }
        float* r0 = (float*)As;
        float* r1 = r0 + 256;
        r0[t] = a0; r1[t] = a1;
        __syncthreads();
        for (int s = 128; s > 0; s >>= 1) {
            if (t < s) { r0[t] += r0[t + s]; r1[t] += r1[t + s]; }
            __syncthreads();
        }
        if (t == 0) { part[2 * db] = r0[0]; part[2 * db + 1] = r1[0]; }
        return;
    }
    if (bid >= 512) {
        // ---- scatter (deterministic positions fixed later by LDS binsort) ----
        const int e = (bid - 512) * 256 + t;
        const int d = edst[e];
        const int p = starts[d] + atomicAdd(&cursor[d], 1);
        sorted[p] = esrc[e];
        return;
    }
    const int bx = bid & 31, by = (bid >> 5) & 3, bz = bid >> 7;
    const int lane = t & 63, w = t >> 6;
    const int wr = w >> 1, wc = w & 1;
    const int l15 = lane & 15, l4 = lane >> 4;
    const int m0 = bx * 128, n0 = by * 128;
    const int kbase = bz * (K / 4);

    f32x4 acc[4][4];
#pragma unroll
    for (int i = 0; i < 4; ++i)
#pragma unroll
        for (int j = 0; j < 4; ++j) acc[i][j] = (f32x4){0.f, 0.f, 0.f, 0.f};

    // tile 128 rows x 8 chunks(16B); source col XOR-swizzled by row&7 (invariant across +32).
    const int ar = t >> 3;
    const int ac = (t & 7) ^ (ar & 7);
    const unsigned short* ga = A + (size_t)(m0 + ar) * K + kbase + ac * 8;
    const unsigned short* gb = Bt + (size_t)(n0 + ar) * K + kbase + ac * 8;

    auto stage = [&](int kt, int buf) {
        const int ko = kt * 64;
        unsigned short* Ad = As + buf * 8192 + t * 8;
        unsigned short* Bd = Bs + buf * 8192 + t * 8;
        GLOAD(ga + ko, Ad);
        GLOAD(ga + (size_t)32 * K + ko, Ad + 2048);
        GLOAD(ga + (size_t)64 * K + ko, Ad + 4096);
        GLOAD(ga + (size_t)96 * K + ko, Ad + 6144);
        GLOAD(gb + ko, Bd);
        GLOAD(gb + (size_t)32 * K + ko, Bd + 2048);
        GLOAD(gb + (size_t)64 * K + ko, Bd + 4096);
        GLOAD(gb + (size_t)96 * K + ko, Bd + 6144);
    };

    const int rsw = l15 & 7;
    const int nk = (K / 4) >> 6;          // 16
    stage(0, 0);
    __syncthreads();
    for (int kt = 0; kt < nk; ++kt) {
        const int cur = kt & 1;
        if (kt + 1 < nk) stage(kt + 1, cur ^ 1);
        const unsigned short* Ac = As + cur * 8192;
        const unsigned short* Bc = Bs + cur * 8192;
        short8 aF[4][2], bF[4][2];
#pragma unroll
        for (int i = 0; i < 4; ++i)
#pragma unroll
            for (int ks = 0; ks < 2; ++ks)
                aF[i][ks] = *(const short8*)(Ac + (wr * 64 + i * 16 + l15) * 64
                                                + (((ks * 4 + l4) ^ rsw) * 8));
#pragma unroll
        for (int j = 0; j < 4; ++j)
#pragma unroll
            for (int ks = 0; ks < 2; ++ks)
                bF[j][ks] = *(const short8*)(Bc + (wc * 64 + j * 16 + l15) * 64
                                                + (((ks * 4 + l4) ^ rsw) * 8));
#pragma unroll
        for (int ks = 0; ks < 2; ++ks)
#pragma unroll
            for (int i = 0; i < 4; ++i)
#pragma unroll
                for (int j = 0; j < 4; ++j)
                    acc[i][j] = __builtin_amdgcn_mfma_f32_16x16x32_bf16(aF[i][ks], bF[j][ks], acc[i][j], 0, 0, 0);
        __syncthreads();
    }

    float* op = outf + (size_t)bz * NN * N;
    const int mrow = m0 + wr * 64;
#pragma unroll
    for (int j = 0; j < 4; ++j) {
        const int cg = n0 + wc * 64 + j * 16 + l15;
#pragma unroll
        for (int i = 0; i < 4; ++i)
#pragma unroll
            for (int r = 0; r < 4; ++r)
                __builtin_nontemporal_store(acc[i][j][r],
                    op + (size_t)(mrow + i * 16 + l4 * 4 + r) * N + cg);
    }
}

// ---------------- red4b (blocks 0..2047) + LDS per-bin insertion sort (blocks 2048..2063) ----------------
#define SORTCAP 6144
__global__ __launch_bounds__(256) void k_redsortb(const float* __restrict__ p,
                                                  unsigned short* __restrict__ G0b,
                                                  const int* __restrict__ starts,
                                                  int* __restrict__ a) {
    __shared__ int buf[SORTCAP];          // 24 KiB
    const int bid = blockIdx.x;
    const int t = threadIdx.x;
    if (bid >= 2048) {
        const int binbase = (bid - 2048) * 256;
        const int lo = starts[binbase], hi = starts[binbase + 256];
        const int n = hi - lo;
        if (n <= SORTCAP) {
            for (int i = t; i < n; i += 256) buf[i] = a[lo + i];
            __syncthreads();
            const int d = binbase + t;
            const int s = starts[d] - lo, e = starts[d + 1] - lo;
            for (int i = s + 1; i < e; ++i) {
                int v = buf[i]; int j = i - 1;
                while (j >= s && buf[j] > v) { buf[j + 1] = buf[j]; --j; }
                buf[j + 1] = v;
            }
            __syncthreads();
            for (int i = t; i < n; i += 256) a[lo + i] = buf[i];
        } else {
            const int d = binbase + t;
            const int s = starts[d], e = starts[d + 1];
            for (int i = s + 1; i < e; ++i) {
                int v = a[i]; int j = i - 1;
                while (j >= s && a[j] > v) { a[j + 1] = a[j]; --j; }
                a[j + 1] = v;
            }
        }
        return;
    }
    const long S = (long)NN * HH / 4;
    long i = bid * 256L + t;
    const f4* pp = (const f4*)p;
    f4 x = __builtin_nontemporal_load(pp + i);
    f4 y = __builtin_nontemporal_load(pp + i + S);
    f4 c = __builtin_nontemporal_load(pp + i + 2 * S);
    f4 d4 = __builtin_nontemporal_load(pp + i + 3 * S);
    us4 o;
    o.x = f2bf((x.x + y.x) + (c.x + d4.x));
    o.y = f2bf((x.y + y.y) + (c.y + d4.y));
    o.z = f2bf((x.z + y.z) + (c.z + d4.z));
    o.w = f2bf((x.w + y.w) + (c.w + d4.w));
    ((us4*)G0b)[i] = o;
}

// ---------------- H-GEMM: 128x64 tile, BK=64, 4 waves (each 64x32, acc 4x2), swizzled ----------------
// grid (32, 8) = 256 blocks. EPI 1: +bias,BN,ReLU -> bf16. EPI 3: +bias,BN,ReLU,BN,ReLU (+DOT).
// STOREH=false skips the output store (last layer: h only feeds the fused dot).
template<int EPI, bool DOT, bool STOREH>
__global__ __launch_bounds__(256) void k_gemmH(
    const unsigned short* __restrict__ A, const unsigned short* __restrict__ Bt,
    const float* __restrict__ bias,
    const float* __restrict__ g1, const float* __restrict__ b1,
    const float* __restrict__ m1, const float* __restrict__ v1,
    const float* __restrict__ g2, const float* __restrict__ b2,
    const float* __restrict__ m2, const float* __restrict__ v2,
    unsigned short* __restrict__ outb,
    const float* __restrict__ wq, float* __restrict__ part, int slotbase)
{
    constexpr int K = HH, N = HH;
    __shared__ alignas(16) unsigned short As[2 * 8192];   // 2 x 128x64 = 32 KiB
    __shared__ alignas(16) unsigned short Bs[2 * 4096];   // 2 x 64x64 = 16 KiB
    const int t = threadIdx.x;
    const int lane = t & 63, w = t >> 6;
    const int wr = w >> 1, wc = w & 1;                    // wave = 64 rows x 32 cols
    const int l15 = lane & 15, l4 = lane >> 4;
    const int m0 = blockIdx.x * 128, n0 = blockIdx.y * 64;

    f32x4 acc[4][2];
#pragma unroll
    for (int i = 0; i < 4; ++i)
#pragma unroll
        for (int j = 0; j < 2; ++j) acc[i][j] = (f32x4){0.f, 0.f, 0.f, 0.f};

    const int ar = t >> 3;
    const int ac = (t & 7) ^ (ar & 7);
    const unsigned short* ga = A + (size_t)(m0 + ar) * K + ac * 8;
    const unsigned short* gb = Bt + (size_t)(n0 + ar) * K + ac * 8;

    auto stage = [&](int kt, int buf) {
        const int ko = kt * 64;
        unsigned short* Ad = As + buf * 8192 + t * 8;
        unsigned short* Bd = Bs + buf * 4096 + t * 8;
        GLOAD(ga + ko, Ad);
        GLOAD(ga + (size_t)32 * K + ko, Ad + 2048);
        GLOAD(ga + (size_t)64 * K + ko, Ad + 4096);
        GLOAD(ga + (size_t)96 * K + ko, Ad + 6144);
        GLOAD(gb + ko, Bd);
        GLOAD(gb + (size_t)32 * K + ko, Bd + 2048);
    };

    const int rsw = l15 & 7;
    const int nk = K >> 6;                // 8
    stage(0, 0);
    __syncthreads();
    for (int kt = 0; kt < nk; ++kt) {
        const int cur = kt & 1;
        if (kt + 1 < nk) stage(kt + 1, cur ^ 1);
        const unsigned short* Ac = As + cur * 8192;
        const unsigned short* Bc = Bs + cur * 4096;
        short8 aF[4][2], bF[2][2];
#pragma unroll
        for (int i = 0; i < 4; ++i)
#pragma unroll
            for (int ks = 0; ks < 2; ++ks)
                aF[i][ks] = *(const short8*)(Ac + (wr * 64 + i * 16 + l15) * 64
                                                + (((ks * 4 + l4) ^ rsw) * 8));
#pragma unroll
        for (int j = 0; j < 2; ++j)
#pragma unroll
            for (int ks = 0; ks < 2; ++ks)
                bF[j][ks] = *(const short8*)(Bc + (wc * 32 + j * 16 + l15) * 64
                                                + (((ks * 4 + l4) ^ rsw) * 8));
#pragma unroll
        for (int ks = 0; ks < 2; ++ks)
#pragma unroll
            for (int i = 0; i < 4; ++i)
#pragma unroll
                for (int j = 0; j < 2; ++j)
                    acc[i][j] = __builtin_amdgcn_mfma_f32_16x16x32_bf16(aF[i][ks], bF[j][ks], acc[i][j], 0, 0, 0);
        __syncthreads();
    }

    const int mrow = m0 + wr * 64;
    float d0 = 0.f, d1 = 0.f;
#pragma unroll
    for (int j = 0; j < 2; ++j) {
        const int cg = n0 + wc * 32 + j * 16 + l15;
        const float bi = bias[cg];
        const float sc1 = rsqrtf(v1[cg] + 1e-5f) * g1[cg];
        const float sh1 = b1[cg] - m1[cg] * sc1;
        float sc2 = 1.f, sh2 = 0.f;
        if (EPI == 3) {
            sc2 = rsqrtf(v2[cg] + 1e-5f) * g2[cg];
            sh2 = b2[cg] - m2[cg] * sc2;
        }
#pragma unroll
        for (int i = 0; i < 4; ++i) {
#pragma unroll
            for (int r = 0; r < 4; ++r) {
                const int rg = mrow + i * 16 + l4 * 4 + r;
                float x = acc[i][j][r];
                x = fmaxf((x + bi) * sc1 + sh1, 0.f);
                if (EPI == 3) x = fmaxf(x * sc2 + sh2, 0.f);
                if constexpr (STOREH) outb[(size_t)rg * N + cg] = f2bf(x);
                if constexpr (DOT) {
                    f2 wvv = __builtin_nontemporal_load((const f2*)wq + (size_t)rg * N + cg);
                    d0 += x * wvv.x; d1 += x * wvv.y;
                }
            }
        }
    }
    if constexpr (DOT) {
        float* r0 = (float*)As;
        float* r1 = r0 + 256;
        __syncthreads();
        r0[t] = d0; r1[t] = d1;
        __syncthreads();
        for (int s = 128; s > 0; s >>= 1) {
            if (t < s) { r0[t] += r0[t + s]; r1[t] += r1[t + s]; }
            __syncthreads();
        }
        if (t == 0) {
            const int slot = slotbase + blockIdx.y * gridDim.x + blockIdx.x;
            part[2 * slot] = r0[0]; part[2 * slot + 1] = r1[0];
        }
    }
}

// ---------------- edge aggregation (gather-sum over sorted in-edges, 8x prefetch) ----------------
__global__ __launch_bounds__(128) void k_agg0(
    const unsigned short* __restrict__ G0, const int* __restrict__ starts,
    const int* __restrict__ sorted, const float* __restrict__ epsp,
    const float* __restrict__ bias,
    const float* __restrict__ bg, const float* __restrict__ bb,
    const float* __restrict__ bm, const float* __restrict__ bv,
    unsigned short* __restrict__ outb)
{
    const int d = blockIdx.x, t = threadIdx.x;
    const float ep = 1.0f + epsp[0];
    ushort4 ow = ((const ushort4*)(G0 + (size_t)d * HH))[t];
    float sx = 0.f, sy = 0.f, sz = 0.f, sw = 0.f;
    const int e0 = starts[d], e1 = starts[d + 1];
    int i = e0;
    for (; i + 8 <= e1; i += 8) {
        ushort4 x[8];
#pragma unroll
        for (int k = 0; k < 8; ++k)
            x[k] = ((const ushort4*)(G0 + (size_t)sorted[i + k] * HH))[t];
#pragma unroll
        for (int k = 0; k < 8; ++k) {
            sx += b2f(x[k].x); sy += b2f(x[k].y); sz += b2f(x[k].z); sw += b2f(x[k].w);
        }
    }
    for (; i < e1; ++i) {
        ushort4 x = ((const ushort4*)(G0 + (size_t)sorted[i] * HH))[t];
        sx += b2f(x.x); sy += b2f(x.y); sz += b2f(x.z); sw += b2f(x.w);
    }
    float4 bi = ((const float4*)bias)[t];
    float4 g4 = ((const float4*)bg)[t];
    float4 b4 = ((const float4*)bb)[t];
    float4 m4 = ((const float4*)bm)[t];
    float4 v4 = ((const float4*)bv)[t];
    float x0 = ep * b2f(ow.x) + sx + bi.x;
    float x1 = ep * b2f(ow.y) + sy + bi.y;
    float x2 = ep * b2f(ow.z) + sz + bi.z;
    float x3 = ep * b2f(ow.w) + sw + bi.w;
    x0 = fmaxf((x0 - m4.x) * rsqrtf(v4.x + 1e-5f) * g4.x + b4.x, 0.f);
    x1 = fmaxf((x1 - m4.y) * rsqrtf(v4.y + 1e-5f) * g4.y + b4.y, 0.f);
    x2 = fmaxf((x2 - m4.z) * rsqrtf(v4.z + 1e-5f) * g4.z + b4.z, 0.f);
    x3 = fmaxf((x3 - m4.w) * rsqrtf(v4.w + 1e-5f) * g4.w + b4.w, 0.f);
    ushort4 o; o.x = f2bf(x0); o.y = f2bf(x1); o.z = f2bf(x2); o.w = f2bf(x3);
    ((ushort4*)(outb + (size_t)d * HH))[t] = o;
}

__global__ __launch_bounds__(128) void k_aggL(
    const unsigned short* __restrict__ hsrc, const int* __restrict__ starts,
    const int* __restrict__ sorted, const float* __restrict__ epsp,
    unsigned short* __restrict__ outb)
{
    const int d = blockIdx.x, t = threadIdx.x;
    const float ep = 1.0f + epsp[0];
    ushort4 ow = ((const ushort4*)(hsrc + (size_t)d * HH))[t];
    float sx = 0.f, sy = 0.f, sz = 0.f, sw = 0.f;
    const int e0 = starts[d], e1 = starts[d + 1];
    int i = e0;
    for (; i + 8 <= e1; i += 8) {
        ushort4 x[8];
#pragma unroll
        for (int k = 0; k < 8; ++k)
            x[k] = ((const ushort4*)(hsrc + (size_t)sorted[i + k] * HH))[t];
#pragma unroll
        for (int k = 0; k < 8; ++k) {
            sx += b2f(x[k].x); sy += b2f(x[k].y); sz += b2f(x[k].z); sw += b2f(x[k].w);
        }
    }
    for (; i < e1; ++i) {
        ushort4 x = ((const ushort4*)(hsrc + (size_t)sorted[i] * HH))[t];
        sx += b2f(x.x); sy += b2f(x.y); sz += b2f(x.z); sw += b2f(x.w);
    }
    ushort4 o;
    o.x = f2bf(ep * b2f(ow.x) + sx);
    o.y = f2bf(ep * b2f(ow.y) + sy);
    o.z = f2bf(ep * b2f(ow.z) + sz);
    o.w = f2bf(ep * b2f(ow.w) + sw);
    ((ushort4*)(outb + (size_t)d * HH))[t] = o;
}

__global__ __launch_bounds__(256) void k_final(const float* __restrict__ part, int nslot,
                                               const float* __restrict__ bp0, const float* __restrict__ bpR,
                                               float* __restrict__ out) {
    __shared__ float s0[256], s1[256];
    int t = threadIdx.x;
    float a0 = 0.f, a1 = 0.f;
    for (int i = t; i < nslot; i += 256) { a0 += part[2 * i]; a1 += part[2 * i + 1]; }
    s0[t] = a0; s1[t] = a1;
    __syncthreads();
    for (int s = 128; s > 0; s >>= 1) {
        if (t < s) { s0[t] += s0[t + s]; s1[t] += s1[t + s]; }
        __syncthreads();
    }
    if (t == 0) {
        out[0] = s0[0] + bp0[0] + bpR[0] + bpR[2] + bpR[4] + bpR[6];
        out[1] = s1[0] + bp0[1] + bpR[1] + bpR[3] + bpR[5] + bpR[7];
    }
}

extern "C" void kernel_launch(void* const* d_in, const int* in_sizes, int n_in,
                              void* d_out, int out_size, void* d_ws, size_t ws_size,
                              hipStream_t stream)
{
    const float* feat = (const float*)d_in[0];
    const int*   esrc = (const int*)d_in[1];
    const int*   edst = (const int*)d_in[2];
    const float* eps0 = (const float*)d_in[3];
    const float* W0a  = (const float*)d_in[4];
    const float* b0a  = (const float*)d_in[5];
    const float* W0b  = (const float*)d_in[6];
    const float* b0b  = (const float*)d_in[7];
    const float* bn0a_g = (const float*)d_in[8];
    const float* bn0a_b = (const float*)d_in[9];
    const float* bn0a_m = (const float*)d_in[10];
    const float* bn0a_v = (const float*)d_in[11];
    const float* bnA0_g = (const float*)d_in[12];
    const float* bnA0_b = (const float*)d_in[13];
    const float* bnA0_m = (const float*)d_in[14];
    const float* bnA0_v = (const float*)d_in[15];
    const float* bnO0_g = (const float*)d_in[16];
    const float* bnO0_b = (const float*)d_in[17];
    const float* bnO0_m = (const float*)d_in[18];
    const float* bnO0_v = (const float*)d_in[19];
    const float* epsR = (const float*)d_in[20];
    const float* WRa  = (const float*)d_in[21];
    const float* bRa  = (const float*)d_in[22];
    const float* WRb  = (const float*)d_in[23];
    const float* bRb  = (const float*)d_in[24];
    const float* bnRa_g = (const float*)d_in[25];
    const float* bnRa_b = (const float*)d_in[26];
    const float* bnRa_m = (const float*)d_in[27];
    const float* bnRa_v = (const float*)d_in[28];
    const float* bnAR_g = (const float*)d_in[29];
    const float* bnAR_b = (const float*)d_in[30];
    const float* bnAR_m = (const float*)d_in[31];
    const float* bnAR_v = (const float*)d_in[32];
    const float* bnOR_g = (const float*)d_in[33];
    const float* bnOR_b = (const float*)d_in[34];
    const float* bnOR_m = (const float*)d_in[35];
    const float* bnOR_v = (const float*)d_in[36];
    const float* Wp0 = (const float*)d_in[37];
    const float* bp0 = (const float*)d_in[38];
    const float* WpR = (const float*)d_in[39];
    const float* bpR = (const float*)d_in[40];
    float* out = (float*)d_out;

    char* ws = (char*)d_ws;
    const size_t MB = 1024 * 1024;
    int*   starts = (int*)(ws + 0x10000);     // [0x10000, 0x14004)
    int*   cursor = (int*)(ws + 0x20000);     // [0x20000, 0x24000)
    int*   sorted = (int*)(ws + 0x30000);     // [0x30000, 0x70000) 256 KiB
    float* part   = (float*)(ws + 0x70000);   // 2048 slots x 2 f32 (16 KiB)
    unsigned short* featb = (unsigned short*)(ws + 1 * MB);    // [4096][4096] bf16, 32 MiB
    unsigned short* w0at  = (unsigned short*)(ws + 33 * MB);   // [512][4096] bf16, 4 MiB
    unsigned short* wt    = (unsigned short*)(ws + 37 * MB);   // 7 x [512][512] bf16
    unsigned short* G0b   = (unsigned short*)(ws + 41 * MB);   // [4096][512] bf16
    unsigned short* xb = (unsigned short*)(ws + 49 * MB);      // [4096][512] bf16
    unsigned short* yb = (unsigned short*)(ws + 53 * MB);      // [4096][512] bf16
    unsigned short* hb = (unsigned short*)(ws + 57 * MB);      // 4 x [4096][512] bf16 (16 MiB)
    float* pbuf = (float*)(ws + 57 * MB);                      // 32 MiB split-K partials,
                                                               // dead before first hb write

    // ---- prep: hist+scan (block 0) + cvt (4096) + weight transposes (3840) ----
    k_prep<<<1 + 4096 + 3840, 256, 0, stream>>>(feat, featb,
                                                W0a, W0b, WRa, WRb, w0at, wt,
                                                edst, starts, cursor);

    // ---- gemm0 (512) + scatter (256) + featb.Wp0 dot (1024) ----
    k_gemm0s<<<1792, 256, 0, stream>>>(featb, w0at, pbuf, esrc, edst, starts, cursor, sorted,
                                       Wp0, part);

    // ---- split-K reduce -> bf16 (2048 blocks) + LDS per-bin sort (16 blocks) ----
    k_redsortb<<<2064, 256, 0, stream>>>(pbuf, G0b, starts, sorted);

    k_agg0<<<NN, 128, 0, stream>>>(G0b, starts, sorted, eps0, b0a,
                                   bn0a_g, bn0a_b, bn0a_m, bn0a_v, xb);

    const dim3 hg(32, 8);   // 256 blocks
    k_gemmH<3, true, true><<<hg, 256, 0, stream>>>(xb, wt,
        b0b, bnA0_g, bnA0_b, bnA0_m, bnA0_v, bnO0_g, bnO0_b, bnO0_m, bnO0_v,
        hb, WpR, part, 1024);

    // ---- layers 1..3 ----
    for (int i = 0; i < 3; ++i) {
        const unsigned short* hp = hb + (size_t)i * NN * HH;
        unsigned short* hn = hb + (size_t)(i + 1) * NN * HH;
        k_aggL<<<NN, 128, 0, stream>>>(hp, starts, sorted, epsR + i, xb);
        k_gemmH<1, false, true><<<hg, 256, 0, stream>>>(xb, wt + (size_t)(1 + i) * HH * HH,
            bRa + (size_t)i * HH,
            bnRa_g + (size_t)i * HH, bnRa_b + (size_t)i * HH, bnRa_m + (size_t)i * HH, bnRa_v + (size_t)i * HH,
            nullptr, nullptr, nullptr, nullptr,
            yb, nullptr, nullptr, 0);
        if (i < 2) {
            k_gemmH<3, true, true><<<hg, 256, 0, stream>>>(yb, wt + (size_t)(4 + i) * HH * HH,
                bRb + (size_t)i * HH,
                bnAR_g + (size_t)i * HH, bnAR_b + (size_t)i * HH, bnAR_m + (size_t)i * HH, bnAR_v + (size_t)i * HH,
                bnOR_g + (size_t)i * HH, bnOR_b + (size_t)i * HH, bnOR_m + (size_t)i * HH, bnOR_v + (size_t)i * HH,
                hn, WpR + (size_t)(i + 1) * NN * HH * 2, part, 1024 + (i + 1) * 256);
        } else {
            // last layer: h4 is dot-only, skip the store
            k_gemmH<3, true, false><<<hg, 256, 0, stream>>>(yb, wt + (size_t)(4 + i) * HH * HH,
                bRb + (size_t)i * HH,
                bnAR_g + (size_t)i * HH, bnAR_b + (size_t)i * HH, bnAR_m + (size_t)i * HH, bnAR_v + (size_t)i * HH,
                bnOR_g + (size_t)i * HH, bnOR_b + (size_t)i * HH, bnOR_m + (size_t)i * HH, bnOR_v + (size_t)i * HH,
                nullptr, WpR + (size_t)(i + 1) * NN * HH * 2, part, 1024 + (i + 1) * 256);
        }
    }

    // ---- jumping-knowledge readout final reduce ----
    k_final<<<1, 256, 0, stream>>>(part, 2048, bp0, bpR, out);
}

// Round 17
// 239.777 us; speedup vs baseline: 1.0856x; 1.0856x over previous
//
#include <hip/hip_runtime.h>
#include <cstdint>
#include <cstddef>

typedef __attribute__((ext_vector_type(8))) short short8;   // 8 bf16 (4 VGPRs)
typedef __attribute__((ext_vector_type(4))) float f32x4;    // 4 fp32 acc
typedef __attribute__((ext_vector_type(4))) float f4;
typedef __attribute__((ext_vector_type(2))) float f2;
typedef __attribute__((ext_vector_type(4))) unsigned short us4;

#define NN 4096
#define HH 512
#define EE 65536

// async global->LDS, 16B per lane (dest must be linear: base + lane*16)
#define GLOAD(gp, lp) __builtin_amdgcn_global_load_lds( \
    (const __attribute__((address_space(1))) void*)(gp), \
    (__attribute__((address_space(3))) void*)(lp), 16, 0, 0)

__device__ __forceinline__ unsigned short f2bf(float x) {
    union { float f; unsigned u; } un; un.f = x;
    unsigned r = un.u + 0x7fffu + ((un.u >> 16) & 1u);   // round-to-nearest-even
    return (unsigned short)(r >> 16);
}
__device__ __forceinline__ float b2f(unsigned short v) {
    union { unsigned u; float f; } un; un.u = ((unsigned)v) << 16; return un.f;
}

// ---------------- prep: hist+scan (block 0) | cvt (1..4096) | transposes (4097..7936) ----------------
__global__ __launch_bounds__(256) void k_prep(const float* __restrict__ feat,
                                              unsigned short* __restrict__ featb,
                                              const float* __restrict__ W0a,
                                              const float* __restrict__ W0b,
                                              const float* __restrict__ WRa,
                                              const float* __restrict__ WRb,
                                              unsigned short* __restrict__ w0at,
                                              unsigned short* __restrict__ wt,
                                              const int* __restrict__ edst,
                                              int* __restrict__ starts,
                                              int* __restrict__ cursor) {
    __shared__ alignas(16) int cnt[NN];          // 16 KiB, overlaid as tile[32][33]
    __shared__ int wtot4[4], woff4[4];
    const int t = threadIdx.x;
    const int bid = blockIdx.x;
    if (bid == 0) {
        // ---- edge histogram + exclusive scan (also zeroes cursor) ----
        for (int i = t; i < NN; i += 256) { cnt[i] = 0; cursor[i] = 0; }
        __syncthreads();
        const int4* e4 = (const int4*)edst;   // 16384 int4
        for (int b = 0; b < 64; b += 8) {
            int4 v[8];
#pragma unroll
            for (int k = 0; k < 8; ++k)
                v[k] = e4[(b + k) * 256 + t];
#pragma unroll
            for (int k = 0; k < 8; ++k) {
                atomicAdd(&cnt[v[k].x], 1); atomicAdd(&cnt[v[k].y], 1);
                atomicAdd(&cnt[v[k].z], 1); atomicAdd(&cnt[v[k].w], 1);
            }
        }
        __syncthreads();
        const int base = t * 16;
        int c[16]; int s = 0;
#pragma unroll
        for (int i = 0; i < 16; ++i) { c[i] = cnt[base + i]; s += c[i]; }
        const int lane = t & 63, wv = t >> 6;
        int inc = s;
        for (int d = 1; d < 64; d <<= 1) {
            int v = __shfl_up(inc, d);
            if (lane >= d) inc += v;
        }
        if (lane == 63) wtot4[wv] = inc;
        __syncthreads();
        if (t == 0) {
            int a = 0;
            for (int i = 0; i < 4; ++i) { woff4[i] = a; a += wtot4[i]; }
            starts[NN] = a;
        }
        __syncthreads();
        int run = woff4[wv] + inc - s;
#pragma unroll
        for (int i = 0; i < 16; ++i) { starts[base + i] = run; run += c[i]; }
    } else if (bid <= 4096) {
        // ---- pure cvt stream: feat f32 -> featb bf16, 16 KiB per block ----
        const int b2 = bid - 1;
        const long B0 = (long)b2 * 1024;
        const f4* ff = (const f4*)feat;
        f4 v[4];
#pragma unroll
        for (int k = 0; k < 4; ++k)
            v[k] = __builtin_nontemporal_load(ff + B0 + k * 256 + t);
#pragma unroll
        for (int k = 0; k < 4; ++k) {
            us4 o;
            o.x = f2bf(v[k].x); o.y = f2bf(v[k].y); o.z = f2bf(v[k].z); o.w = f2bf(v[k].w);
            __builtin_nontemporal_store(o, (us4*)featb + B0 + k * 256 + t);
        }
    } else {
        // ---- weight transpose/convert tiles ----
        float (*tile)[33] = (float(*)[33])cnt;
        const int tix = bid - 4097;
        const float* W; unsigned short* Wt; int K, kb, nb;
        if (tix < 2048) {                 // W0a: 128 x 16 tiles of 32x32
            W = W0a; Wt = w0at; K = NN; kb = tix >> 4; nb = tix & 15;
        } else {
            const int t2 = tix - 2048;    // 7 x 256 tiles
            const int z = t2 >> 8, r = t2 & 255;
            W = (z == 0) ? W0b : (z < 4) ? WRa + (size_t)(z - 1) * HH * HH
                                         : WRb + (size_t)(z - 4) * HH * HH;
            Wt = wt + (size_t)z * HH * HH; K = HH; kb = r >> 4; nb = r & 15;
        }
        const int k0 = kb * 32, n0 = nb * 32;
        const int tx = t & 31, ty = t >> 5;
        for (int r = ty; r < 32; r += 8)
            tile[r][tx] = W[(size_t)(k0 + r) * HH + n0 + tx];
        __syncthreads();
        for (int r = ty; r < 32; r += 8)
            Wt[(size_t)(n0 + r) * K + k0 + tx] = f2bf(tile[tx][r]);
    }
}

// ---------------- gemm0 (blocks 0..511) + edge scatter (blocks 512..767) ----------------
// gemm0: 128x128 tile, BK=64, 4 waves, split-K=4, XOR-swizzled LDS. 2 blocks/CU.
__global__ __launch_bounds__(256) void k_gemm0s(
    const unsigned short* __restrict__ A, const unsigned short* __restrict__ Bt,
    float* __restrict__ outf,
    const int* __restrict__ esrc, const int* __restrict__ edst,
    const int* __restrict__ starts, int* __restrict__ cursor, int* __restrict__ sorted)
{
    constexpr int K = NN, N = HH;
    __shared__ alignas(16) unsigned short As[2 * 8192];   // 2 x 128x64 = 32 KiB
    __shared__ alignas(16) unsigned short Bs[2 * 8192];   // 32 KiB
    const int bid = blockIdx.x;
    const int t = threadIdx.x;
    if (bid >= 512) {
        // ---- scatter (deterministic positions fixed later by LDS binsort) ----
        const int e = (bid - 512) * 256 + t;
        const int d = edst[e];
        const int p = starts[d] + atomicAdd(&cursor[d], 1);
        sorted[p] = esrc[e];
        return;
    }
    const int bx = bid & 31, by = (bid >> 5) & 3, bz = bid >> 7;
    const int lane = t & 63, w = t >> 6;
    const int wr = w >> 1, wc = w & 1;
    const int l15 = lane & 15, l4 = lane >> 4;
    const int m0 = bx * 128, n0 = by * 128;
    const int kbase = bz * (K / 4);

    f32x4 acc[4][4];
#pragma unroll
    for (int i = 0; i < 4; ++i)
#pragma unroll
        for (int j = 0; j < 4; ++j) acc[i][j] = (f32x4){0.f, 0.f, 0.f, 0.f};

    // tile 128 rows x 8 chunks(16B); source col XOR-swizzled by row&7 (invariant across +32).
    const int ar = t >> 3;
    const int ac = (t & 7) ^ (ar & 7);
    const unsigned short* ga = A + (size_t)(m0 + ar) * K + kbase + ac * 8;
    const unsigned short* gb = Bt + (size_t)(n0 + ar) * K + kbase + ac * 8;

    auto stage = [&](int kt, int buf) {
        const int ko = kt * 64;
        unsigned short* Ad = As + buf * 8192 + t * 8;
        unsigned short* Bd = Bs + buf * 8192 + t * 8;
        GLOAD(ga + ko, Ad);
        GLOAD(ga + (size_t)32 * K + ko, Ad + 2048);
        GLOAD(ga + (size_t)64 * K + ko, Ad + 4096);
        GLOAD(ga + (size_t)96 * K + ko, Ad + 6144);
        GLOAD(gb + ko, Bd);
        GLOAD(gb + (size_t)32 * K + ko, Bd + 2048);
        GLOAD(gb + (size_t)64 * K + ko, Bd + 4096);
        GLOAD(gb + (size_t)96 * K + ko, Bd + 6144);
    };

    const int rsw = l15 & 7;
    const int nk = (K / 4) >> 6;          // 16
    stage(0, 0);
    __syncthreads();
    for (int kt = 0; kt < nk; ++kt) {
        const int cur = kt & 1;
        if (kt + 1 < nk) stage(kt + 1, cur ^ 1);
        const unsigned short* Ac = As + cur * 8192;
        const unsigned short* Bc = Bs + cur * 8192;
        short8 aF[4][2], bF[4][2];
#pragma unroll
        for (int i = 0; i < 4; ++i)
#pragma unroll
            for (int ks = 0; ks < 2; ++ks)
                aF[i][ks] = *(const short8*)(Ac + (wr * 64 + i * 16 + l15) * 64
                                                + (((ks * 4 + l4) ^ rsw) * 8));
#pragma unroll
        for (int j = 0; j < 4; ++j)
#pragma unroll
            for (int ks = 0; ks < 2; ++ks)
                bF[j][ks] = *(const short8*)(Bc + (wc * 64 + j * 16 + l15) * 64
                                                + (((ks * 4 + l4) ^ rsw) * 8));
#pragma unroll
        for (int ks = 0; ks < 2; ++ks)
#pragma unroll
            for (int i = 0; i < 4; ++i)
#pragma unroll
                for (int j = 0; j < 4; ++j)
                    acc[i][j] = __builtin_amdgcn_mfma_f32_16x16x32_bf16(aF[i][ks], bF[j][ks], acc[i][j], 0, 0, 0);
        __syncthreads();
    }

    float* op = outf + (size_t)bz * NN * N;
    const int mrow = m0 + wr * 64;
#pragma unroll
    for (int j = 0; j < 4; ++j) {
        const int cg = n0 + wc * 64 + j * 16 + l15;
#pragma unroll
        for (int i = 0; i < 4; ++i)
#pragma unroll
            for (int r = 0; r < 4; ++r)
                __builtin_nontemporal_store(acc[i][j][r],
                    op + (size_t)(mrow + i * 16 + l4 * 4 + r) * N + cg);
    }
}

// ---- red4b (0..2047) + LDS bin sort (2048..2063) + featb.Wp0 readout dot (2064..3087) ----
// 24 KiB LDS -> ~6 blocks/CU: the 160 MiB dot stream runs at proper occupancy here.
#define SORTCAP 6144
__global__ __launch_bounds__(256) void k_redsortb(const float* __restrict__ p,
                                                  unsigned short* __restrict__ G0b,
                                                  const int* __restrict__ starts,
                                                  int* __restrict__ a,
                                                  const unsigned short* __restrict__ featb,
                                                  const float* __restrict__ Wp0,
                                                  float* __restrict__ part) {
    __shared__ int buf[SORTCAP];          // 24 KiB
    const int bid = blockIdx.x;
    const int t = threadIdx.x;
    if (bid >= 2064) {
        // ---- featb . Wp0 partial dot (bf16 feat; error ~1e-2, far below threshold) ----
        const int db = bid - 2064;                // 0..1023
        const long c0 = (long)db * 2048;          // 8-elem chunk base (16384 elems/block)
        const short8* fb = (const short8*)featb;
        const f4* wp = (const f4*)Wp0;
        float a0 = 0.f, a1 = 0.f;
#pragma unroll
        for (int k = 0; k < 8; ++k) {
            const long ci = c0 + k * 256 + t;
            short8 fv = fb[ci];
            f4 w0 = __builtin_nontemporal_load(wp + ci * 4);
            f4 w1 = __builtin_nontemporal_load(wp + ci * 4 + 1);
            f4 w2 = __builtin_nontemporal_load(wp + ci * 4 + 2);
            f4 w3 = __builtin_nontemporal_load(wp + ci * 4 + 3);
            float f0 = b2f((unsigned short)fv[0]), f1 = b2f((unsigned short)fv[1]);
            float f2v = b2f((unsigned short)fv[2]), f3 = b2f((unsigned short)fv[3]);
            float f4v = b2f((unsigned short)fv[4]), f5 = b2f((unsigned short)fv[5]);
            float f6 = b2f((unsigned short)fv[6]), f7 = b2f((unsigned short)fv[7]);
            a0 += f0 * w0.x + f1 * w0.z + f2v * w1.x + f3 * w1.z
                + f4v * w2.x + f5 * w2.z + f6 * w3.x + f7 * w3.z;
            a1 += f0 * w0.y + f1 * w0.w + f2v * w1.y + f3 * w1.w
                + f4v * w2.y + f5 * w2.w + f6 * w3.y + f7 * w3.w;
        }
        float* r0 = (float*)buf;
        float* r1 = r0 + 256;
        r0[t] = a0; r1[t] = a1;
        __syncthreads();
        for (int s = 128; s > 0; s >>= 1) {
            if (t < s) { r0[t] += r0[t + s]; r1[t] += r1[t + s]; }
            __syncthreads();
        }
        if (t == 0) { part[2 * db] = r0[0]; part[2 * db + 1] = r1[0]; }
        return;
    }
    if (bid >= 2048) {
        const int binbase = (bid - 2048) * 256;
        const int lo = starts[binbase], hi = starts[binbase + 256];
        const int n = hi - lo;
        if (n <= SORTCAP) {
            for (int i = t; i < n; i += 256) buf[i] = a[lo + i];
            __syncthreads();
            const int d = binbase + t;
            const int s = starts[d] - lo, e = starts[d + 1] - lo;
            for (int i = s + 1; i < e; ++i) {
                int v = buf[i]; int j = i - 1;
                while (j >= s && buf[j] > v) { buf[j + 1] = buf[j]; --j; }
                buf[j + 1] = v;
            }
            __syncthreads();
            for (int i = t; i < n; i += 256) a[lo + i] = buf[i];
        } else {
            const int d = binbase + t;
            const int s = starts[d], e = starts[d + 1];
            for (int i = s + 1; i < e; ++i) {
                int v = a[i]; int j = i - 1;
                while (j >= s && a[j] > v) { a[j + 1] = a[j]; --j; }
                a[j + 1] = v;
            }
        }
        return;
    }
    const long S = (long)NN * HH / 4;
    long i = bid * 256L + t;
    const f4* pp = (const f4*)p;
    f4 x = __builtin_nontemporal_load(pp + i);
    f4 y = __builtin_nontemporal_load(pp + i + S);
    f4 c = __builtin_nontemporal_load(pp + i + 2 * S);
    f4 d4 = __builtin_nontemporal_load(pp + i + 3 * S);
    us4 o;
    o.x = f2bf((x.x + y.x) + (c.x + d4.x));
    o.y = f2bf((x.y + y.y) + (c.y + d4.y));
    o.z = f2bf((x.z + y.z) + (c.z + d4.z));
    o.w = f2bf((x.w + y.w) + (c.w + d4.w));
    ((us4*)G0b)[i] = o;
}

// ---------------- H-GEMM: 128x64 tile, BK=64, 4 waves (each 64x32, acc 4x2), swizzled ----------------
// grid (32, 8) = 256 blocks. EPI 1: +bias,BN,ReLU -> bf16. EPI 3: +bias,BN,ReLU,BN,ReLU (+DOT).
// STOREH=false skips the output store (last layer: h only feeds the fused dot).
template<int EPI, bool DOT, bool STOREH>
__global__ __launch_bounds__(256) void k_gemmH(
    const unsigned short* __restrict__ A, const unsigned short* __restrict__ Bt,
    const float* __restrict__ bias,
    const float* __restrict__ g1, const float* __restrict__ b1,
    const float* __restrict__ m1, const float* __restrict__ v1,
    const float* __restrict__ g2, const float* __restrict__ b2,
    const float* __restrict__ m2, const float* __restrict__ v2,
    unsigned short* __restrict__ outb,
    const float* __restrict__ wq, float* __restrict__ part, int slotbase)
{
    constexpr int K = HH, N = HH;
    __shared__ alignas(16) unsigned short As[2 * 8192];   // 2 x 128x64 = 32 KiB
    __shared__ alignas(16) unsigned short Bs[2 * 4096];   // 2 x 64x64 = 16 KiB
    const int t = threadIdx.x;
    const int lane = t & 63, w = t >> 6;
    const int wr = w >> 1, wc = w & 1;                    // wave = 64 rows x 32 cols
    const int l15 = lane & 15, l4 = lane >> 4;
    const int m0 = blockIdx.x * 128, n0 = blockIdx.y * 64;

    f32x4 acc[4][2];
#pragma unroll
    for (int i = 0; i < 4; ++i)
#pragma unroll
        for (int j = 0; j < 2; ++j) acc[i][j] = (f32x4){0.f, 0.f, 0.f, 0.f};

    const int ar = t >> 3;
    const int ac = (t & 7) ^ (ar & 7);
    const unsigned short* ga = A + (size_t)(m0 + ar) * K + ac * 8;
    const unsigned short* gb = Bt + (size_t)(n0 + ar) * K + ac * 8;

    auto stage = [&](int kt, int buf) {
        const int ko = kt * 64;
        unsigned short* Ad = As + buf * 8192 + t * 8;
        unsigned short* Bd = Bs + buf * 4096 + t * 8;
        GLOAD(ga + ko, Ad);
        GLOAD(ga + (size_t)32 * K + ko, Ad + 2048);
        GLOAD(ga + (size_t)64 * K + ko, Ad + 4096);
        GLOAD(ga + (size_t)96 * K + ko, Ad + 6144);
        GLOAD(gb + ko, Bd);
        GLOAD(gb + (size_t)32 * K + ko, Bd + 2048);
    };

    const int rsw = l15 & 7;
    const int nk = K >> 6;                // 8
    stage(0, 0);
    __syncthreads();
    for (int kt = 0; kt < nk; ++kt) {
        const int cur = kt & 1;
        if (kt + 1 < nk) stage(kt + 1, cur ^ 1);
        const unsigned short* Ac = As + cur * 8192;
        const unsigned short* Bc = Bs + cur * 4096;
        short8 aF[4][2], bF[2][2];
#pragma unroll
        for (int i = 0; i < 4; ++i)
#pragma unroll
            for (int ks = 0; ks < 2; ++ks)
                aF[i][ks] = *(const short8*)(Ac + (wr * 64 + i * 16 + l15) * 64
                                                + (((ks * 4 + l4) ^ rsw) * 8));
#pragma unroll
        for (int j = 0; j < 2; ++j)
#pragma unroll
            for (int ks = 0; ks < 2; ++ks)
                bF[j][ks] = *(const short8*)(Bc + (wc * 32 + j * 16 + l15) * 64
                                                + (((ks * 4 + l4) ^ rsw) * 8));
#pragma unroll
        for (int ks = 0; ks < 2; ++ks)
#pragma unroll
            for (int i = 0; i < 4; ++i)
#pragma unroll
                for (int j = 0; j < 2; ++j)
                    acc[i][j] = __builtin_amdgcn_mfma_f32_16x16x32_bf16(aF[i][ks], bF[j][ks], acc[i][j], 0, 0, 0);
        __syncthreads();
    }

    const int mrow = m0 + wr * 64;
    float d0 = 0.f, d1 = 0.f;
#pragma unroll
    for (int j = 0; j < 2; ++j) {
        const int cg = n0 + wc * 32 + j * 16 + l15;
        const float bi = bias[cg];
        const float sc1 = rsqrtf(v1[cg] + 1e-5f) * g1[cg];
        const float sh1 = b1[cg] - m1[cg] * sc1;
        float sc2 = 1.f, sh2 = 0.f;
        if (EPI == 3) {
            sc2 = rsqrtf(v2[cg] + 1e-5f) * g2[cg];
            sh2 = b2[cg] - m2[cg] * sc2;
        }
#pragma unroll
        for (int i = 0; i < 4; ++i) {
#pragma unroll
            for (int r = 0; r < 4; ++r) {
                const int rg = mrow + i * 16 + l4 * 4 + r;
                float x = acc[i][j][r];
                x = fmaxf((x + bi) * sc1 + sh1, 0.f);
                if (EPI == 3) x = fmaxf(x * sc2 + sh2, 0.f);
                if constexpr (STOREH) outb[(size_t)rg * N + cg] = f2bf(x);
                if constexpr (DOT) {
                    f2 wvv = __builtin_nontemporal_load((const f2*)wq + (size_t)rg * N + cg);
                    d0 += x * wvv.x; d1 += x * wvv.y;
                }
            }
        }
    }
    if constexpr (DOT) {
        float* r0 = (float*)As;
        float* r1 = r0 + 256;
        __syncthreads();
        r0[t] = d0; r1[t] = d1;
        __syncthreads();
        for (int s = 128; s > 0; s >>= 1) {
            if (t < s) { r0[t] += r0[t + s]; r1[t] += r1[t + s]; }
            __syncthreads();
        }
        if (t == 0) {
            const int slot = slotbase + blockIdx.y * gridDim.x + blockIdx.x;
            part[2 * slot] = r0[0]; part[2 * slot + 1] = r1[0];
        }
    }
}

// ---------------- edge aggregation (gather-sum over sorted in-edges, 8x prefetch) ----------------
__global__ __launch_bounds__(128) void k_agg0(
    const unsigned short* __restrict__ G0, const int* __restrict__ starts,
    const int* __restrict__ sorted, const float* __restrict__ epsp,
    const float* __restrict__ bias,
    const float* __restrict__ bg, const float* __restrict__ bb,
    const float* __restrict__ bm, const float* __restrict__ bv,
    unsigned short* __restrict__ outb)
{
    const int d = blockIdx.x, t = threadIdx.x;
    const float ep = 1.0f + epsp[0];
    ushort4 ow = ((const ushort4*)(G0 + (size_t)d * HH))[t];
    float sx = 0.f, sy = 0.f, sz = 0.f, sw = 0.f;
    const int e0 = starts[d], e1 = starts[d + 1];
    int i = e0;
    for (; i + 8 <= e1; i += 8) {
        ushort4 x[8];
#pragma unroll
        for (int k = 0; k < 8; ++k)
            x[k] = ((const ushort4*)(G0 + (size_t)sorted[i + k] * HH))[t];
#pragma unroll
        for (int k = 0; k < 8; ++k) {
            sx += b2f(x[k].x); sy += b2f(x[k].y); sz += b2f(x[k].z); sw += b2f(x[k].w);
        }
    }
    for (; i < e1; ++i) {
        ushort4 x = ((const ushort4*)(G0 + (size_t)sorted[i] * HH))[t];
        sx += b2f(x.x); sy += b2f(x.y); sz += b2f(x.z); sw += b2f(x.w);
    }
    float4 bi = ((const float4*)bias)[t];
    float4 g4 = ((const float4*)bg)[t];
    float4 b4 = ((const float4*)bb)[t];
    float4 m4 = ((const float4*)bm)[t];
    float4 v4 = ((const float4*)bv)[t];
    float x0 = ep * b2f(ow.x) + sx + bi.x;
    float x1 = ep * b2f(ow.y) + sy + bi.y;
    float x2 = ep * b2f(ow.z) + sz + bi.z;
    float x3 = ep * b2f(ow.w) + sw + bi.w;
    x0 = fmaxf((x0 - m4.x) * rsqrtf(v4.x + 1e-5f) * g4.x + b4.x, 0.f);
    x1 = fmaxf((x1 - m4.y) * rsqrtf(v4.y + 1e-5f) * g4.y + b4.y, 0.f);
    x2 = fmaxf((x2 - m4.z) * rsqrtf(v4.z + 1e-5f) * g4.z + b4.z, 0.f);
    x3 = fmaxf((x3 - m4.w) * rsqrtf(v4.w + 1e-5f) * g4.w + b4.w, 0.f);
    ushort4 o; o.x = f2bf(x0); o.y = f2bf(x1); o.z = f2bf(x2); o.w = f2bf(x3);
    ((ushort4*)(outb + (size_t)d * HH))[t] = o;
}

__global__ __launch_bounds__(128) void k_aggL(
    const unsigned short* __restrict__ hsrc, const int* __restrict__ starts,
    const int* __restrict__ sorted, const float* __restrict__ epsp,
    unsigned short* __restrict__ outb)
{
    const int d = blockIdx.x, t = threadIdx.x;
    const float ep = 1.0f + epsp[0];
    ushort4 ow = ((const ushort4*)(hsrc + (size_t)d * HH))[t];
    float sx = 0.f, sy = 0.f, sz = 0.f, sw = 0.f;
    const int e0 = starts[d], e1 = starts[d + 1];
    int i = e0;
    for (; i + 8 <= e1; i += 8) {
        ushort4 x[8];
#pragma unroll
        for (int k = 0; k < 8; ++k)
            x[k] = ((const ushort4*)(hsrc + (size_t)sorted[i + k] * HH))[t];
#pragma unroll
        for (int k = 0; k < 8; ++k) {
            sx += b2f(x[k].x); sy += b2f(x[k].y); sz += b2f(x[k].z); sw += b2f(x[k].w);
        }
    }
    for (; i < e1; ++i) {
        ushort4 x = ((const ushort4*)(hsrc + (size_t)sorted[i] * HH))[t];
        sx += b2f(x.x); sy += b2f(x.y); sz += b2f(x.z); sw += b2f(x.w);
    }
    ushort4 o;
    o.x = f2bf(ep * b2f(ow.x) + sx);
    o.y = f2bf(ep * b2f(ow.y) + sy);
    o.z = f2bf(ep * b2f(ow.z) + sz);
    o.w = f2bf(ep * b2f(ow.w) + sw);
    ((ushort4*)(outb + (size_t)d * HH))[t] = o;
}

__global__ __launch_bounds__(256) void k_final(const float* __restrict__ part, int nslot,
                                               const float* __restrict__ bp0, const float* __restrict__ bpR,
                                               float* __restrict__ out) {
    __shared__ float s0[256], s1[256];
    int t = threadIdx.x;
    float a0 = 0.f, a1 = 0.f;
    for (int i = t; i < nslot; i += 256) { a0 += part[2 * i]; a1 += part[2 * i + 1]; }
    s0[t] = a0; s1[t] = a1;
    __syncthreads();
    for (int s = 128; s > 0; s >>= 1) {
        if (t < s) { s0[t] += s0[t + s]; s1[t] += s1[t + s]; }
        __syncthreads();
    }
    if (t == 0) {
        out[0] = s0[0] + bp0[0] + bpR[0] + bpR[2] + bpR[4] + bpR[6];
        out[1] = s1[0] + bp0[1] + bpR[1] + bpR[3] + bpR[5] + bpR[7];
    }
}

extern "C" void kernel_launch(void* const* d_in, const int* in_sizes, int n_in,
                              void* d_out, int out_size, void* d_ws, size_t ws_size,
                              hipStream_t stream)
{
    const float* feat = (const float*)d_in[0];
    const int*   esrc = (const int*)d_in[1];
    const int*   edst = (const int*)d_in[2];
    const float* eps0 = (const float*)d_in[3];
    const float* W0a  = (const float*)d_in[4];
    const float* b0a  = (const float*)d_in[5];
    const float* W0b  = (const float*)d_in[6];
    const float* b0b  = (const float*)d_in[7];
    const float* bn0a_g = (const float*)d_in[8];
    const float* bn0a_b = (const float*)d_in[9];
    const float* bn0a_m = (const float*)d_in[10];
    const float* bn0a_v = (const float*)d_in[11];
    const float* bnA0_g = (const float*)d_in[12];
    const float* bnA0_b = (const float*)d_in[13];
    const float* bnA0_m = (const float*)d_in[14];
    const float* bnA0_v = (const float*)d_in[15];
    const float* bnO0_g = (const float*)d_in[16];
    const float* bnO0_b = (const float*)d_in[17];
    const float* bnO0_m = (const float*)d_in[18];
    const float* bnO0_v = (const float*)d_in[19];
    const float* epsR = (const float*)d_in[20];
    const float* WRa  = (const float*)d_in[21];
    const float* bRa  = (const float*)d_in[22];
    const float* WRb  = (const float*)d_in[23];
    const float* bRb  = (const float*)d_in[24];
    const float* bnRa_g = (const float*)d_in[25];
    const float* bnRa_b = (const float*)d_in[26];
    const float* bnRa_m = (const float*)d_in[27];
    const float* bnRa_v = (const float*)d_in[28];
    const float* bnAR_g = (const float*)d_in[29];
    const float* bnAR_b = (const float*)d_in[30];
    const float* bnAR_m = (const float*)d_in[31];
    const float* bnAR_v = (const float*)d_in[32];
    const float* bnOR_g = (const float*)d_in[33];
    const float* bnOR_b = (const float*)d_in[34];
    const float* bnOR_m = (const float*)d_in[35];
    const float* bnOR_v = (const float*)d_in[36];
    const float* Wp0 = (const float*)d_in[37];
    const float* bp0 = (const float*)d_in[38];
    const float* WpR = (const float*)d_in[39];
    const float* bpR = (const float*)d_in[40];
    float* out = (float*)d_out;

    char* ws = (char*)d_ws;
    const size_t MB = 1024 * 1024;
    int*   starts = (int*)(ws + 0x10000);     // [0x10000, 0x14004)
    int*   cursor = (int*)(ws + 0x20000);     // [0x20000, 0x24000)
    int*   sorted = (int*)(ws + 0x30000);     // [0x30000, 0x70000) 256 KiB
    float* part   = (float*)(ws + 0x70000);   // 2048 slots x 2 f32 (16 KiB)
    unsigned short* featb = (unsigned short*)(ws + 1 * MB);    // [4096][4096] bf16, 32 MiB
    unsigned short* w0at  = (unsigned short*)(ws + 33 * MB);   // [512][4096] bf16, 4 MiB
    unsigned short* wt    = (unsigned short*)(ws + 37 * MB);   // 7 x [512][512] bf16
    unsigned short* G0b   = (unsigned short*)(ws + 41 * MB);   // [4096][512] bf16
    unsigned short* xb = (unsigned short*)(ws + 49 * MB);      // [4096][512] bf16
    unsigned short* yb = (unsigned short*)(ws + 53 * MB);      // [4096][512] bf16
    unsigned short* hb = (unsigned short*)(ws + 57 * MB);      // 4 x [4096][512] bf16 (16 MiB)
    float* pbuf = (float*)(ws + 57 * MB);                      // 32 MiB split-K partials,
                                                               // dead before first hb write

    // ---- prep: hist+scan (block 0) + cvt (4096) + weight transposes (3840) ----
    k_prep<<<1 + 4096 + 3840, 256, 0, stream>>>(feat, featb,
                                                W0a, W0b, WRa, WRb, w0at, wt,
                                                edst, starts, cursor);

    // ---- gemm0 (512 blocks) + edge scatter (256 blocks) ----
    k_gemm0s<<<768, 256, 0, stream>>>(featb, w0at, pbuf, esrc, edst, starts, cursor, sorted);

    // ---- split-K reduce (2048) + LDS bin sort (16) + featb.Wp0 readout dot (1024) ----
    k_redsortb<<<2064 + 1024, 256, 0, stream>>>(pbuf, G0b, starts, sorted,
                                                featb, Wp0, part);

    k_agg0<<<NN, 128, 0, stream>>>(G0b, starts, sorted, eps0, b0a,
                                   bn0a_g, bn0a_b, bn0a_m, bn0a_v, xb);

    const dim3 hg(32, 8);   // 256 blocks
    k_gemmH<3, true, true><<<hg, 256, 0, stream>>>(xb, wt,
        b0b, bnA0_g, bnA0_b, bnA0_m, bnA0_v, bnO0_g, bnO0_b, bnO0_m, bnO0_v,
        hb, WpR, part, 1024);

    // ---- layers 1..3 ----
    for (int i = 0; i < 3; ++i) {
        const unsigned short* hp = hb + (size_t)i * NN * HH;
        unsigned short* hn = hb + (size_t)(i + 1) * NN * HH;
        k_aggL<<<NN, 128, 0, stream>>>(hp, starts, sorted, epsR + i, xb);
        k_gemmH<1, false, true><<<hg, 256, 0, stream>>>(xb, wt + (size_t)(1 + i) * HH * HH,
            bRa + (size_t)i * HH,
            bnRa_g + (size_t)i * HH, bnRa_b + (size_t)i * HH, bnRa_m + (size_t)i * HH, bnRa_v + (size_t)i * HH,
            nullptr, nullptr, nullptr, nullptr,
            yb, nullptr, nullptr, 0);
        if (i < 2) {
            k_gemmH<3, true, true><<<hg, 256, 0, stream>>>(yb, wt + (size_t)(4 + i) * HH * HH,
                bRb + (size_t)i * HH,
                bnAR_g + (size_t)i * HH, bnAR_b + (size_t)i * HH, bnAR_m + (size_t)i * HH, bnAR_v + (size_t)i * HH,
                bnOR_g + (size_t)i * HH, bnOR_b + (size_t)i * HH, bnOR_m + (size_t)i * HH, bnOR_v + (size_t)i * HH,
                hn, WpR + (size_t)(i + 1) * NN * HH * 2, part, 1024 + (i + 1) * 256);
        } else {
            // last layer: h4 is dot-only, skip the store
            k_gemmH<3, true, false><<<hg, 256, 0, stream>>>(yb, wt + (size_t)(4 + i) * HH * HH,
                bRb + (size_t)i * HH,
                bnAR_g + (size_t)i * HH, bnAR_b + (size_t)i * HH, bnAR_m + (size_t)i * HH, bnAR_v + (size_t)i * HH,
                bnOR_g + (size_t)i * HH, bnOR_b + (size_t)i * HH, bnOR_m + (size_t)i * HH, bnOR_v + (size_t)i * HH,
                nullptr, WpR + (size_t)(i + 1) * NN * HH * 2, part, 1024 + (i + 1) * 256);
        }
    }

    // ---- jumping-knowledge readout final reduce ----
    k_final<<<1, 256, 0, stream>>>(part, 2048, bp0, bpR, out);
}